// Round 8
// baseline (123.355 us; speedup 1.0000x reference)
//
#include <hip/hip_runtime.h>
#include <stdint.h>

using short8 = __attribute__((ext_vector_type(8))) short;
using f32x4  = __attribute__((ext_vector_type(4))) float;

__device__ __forceinline__ unsigned short f2bf(float f) {
    unsigned int u = __float_as_uint(f);
    unsigned int r = (u + 0x7fffu + ((u >> 16) & 1u)) >> 16;
    return (unsigned short)r;
}

// ---------------- prep: [0,512) transpose x -> x_t ; [512,640) zero pad rows ; [640,2944) build B ----------------
__global__ __launch_bounds__(256) void k_prep(const float* __restrict__ x,
                                              const float* __restrict__ wgt,
                                              unsigned short* __restrict__ xt,
                                              unsigned short* __restrict__ ball) {
    __shared__ unsigned short sm[256][72];
    int b = blockIdx.x;
    int tid = threadIdx.x;
    if (b < 512) {
        int n = b >> 6; int h = b & 63;
        int c = tid >> 2, r = tid & 3; int k = r * 64 + c;
        const float* src = x + ((((size_t)n * 64 + c) * 4 + r) * 64 + h) * 64;
#pragma unroll
        for (int i = 0; i < 64; i += 4) {
            float4 v = *(const float4*)(src + i);
            sm[k][i + 0] = f2bf(v.x); sm[k][i + 1] = f2bf(v.y);
            sm[k][i + 2] = f2bf(v.z); sm[k][i + 3] = f2bf(v.w);
        }
        __syncthreads();
        int w = tid & 63, kg = tid >> 6;
        unsigned short* dst = xt + ((size_t)(n * 66 + (h + 1)) * 64 + w) * 256;
        int key = (w + 1) & 7;
#pragma unroll
        for (int cc = 0; cc < 8; cc++) {
            int s = kg * 8 + cc; int sp = s ^ key;
            short8 v;
#pragma unroll
            for (int e = 0; e < 8; e++) v[e] = (short)sm[s * 8 + e][w];
            *(short8*)(dst + sp * 8) = v;
        }
    } else if (b < 640) {
        int idx = (b - 512) * 256 + tid;
        int n = idx >> 12; int rr = (idx >> 11) & 1; int cpos = idx & 2047;
        f32x4 z = {0.f, 0.f, 0.f, 0.f};
        *(f32x4*)((char*)xt + (size_t)(n * 66 + (rr ? 65 : 0)) * 32768 + cpos * 16) = z;
    } else {
        int idx = (b - 640) * 256 + tid;
        int k = idx & 255; int col = (idx >> 8) & 255; int j = idx >> 16;
        int rot = col >> 6, o = col & 63;
        int r = k >> 6, c = k & 63;
        int t = (j == 0) ? 0 : (1 + ((j - 1 - 2 * rot) & 7));
        float v = wgt[((o * 64 + c) * 4 + ((r - rot) & 3)) * 9 + t];
        ball[idx] = f2bf(v);
    }
}

// main: block = (n, 2 h-rows); 8 waves = 2(M: h-row) x 4(rot, 64 cols). B once per j in regs.
__global__ __launch_bounds__(512) void k_main(const unsigned short* __restrict__ xt,
                                              const unsigned short* __restrict__ ball,
                                              float* __restrict__ out) {
    extern __shared__ char lds[];                      // 4 rows x 66 slots x 512B = 135168
    int blk = blockIdx.x; int n = blk >> 5; int h0 = (blk & 31) * 2;
    int tid = threadIdx.x;

    // stage 4 x_t rows via async global->LDS (R4-verbatim)
    const char* xbase = (const char*)xt;
#pragma unroll
    for (int i = 0; i < 16; i++) {
        int chunk = tid + i * 512;
        int r4 = chunk >> 11; int cin = chunk & 2047;
        const char* src = xbase + (size_t)(n * 66 + h0 + r4) * 32768 + cin * 16;
        char* dst = lds + r4 * 33792 + 512 + cin * 16;
        __builtin_amdgcn_global_load_lds(
            (const __attribute__((address_space(1))) unsigned int*)src,
            (__attribute__((address_space(3))) unsigned int*)dst, 16, 0, 0);
    }
    if (tid < 256) {                                   // zero the w-halo slots (ws=0, ws=65)
        int r4 = tid >> 6; int sp = (tid >> 5) & 1; int cc = tid & 31;
        f32x4 z = {0.f, 0.f, 0.f, 0.f};
        *(f32x4*)(lds + r4 * 33792 + (sp ? 65 * 512 : 0) + cc * 16) = z;
    }
    __syncthreads();

    int wv = tid >> 6; int l = tid & 63; int l15 = l & 15; int l4 = l >> 4;
    int rot = wv & 3; int mhalf = wv >> 2;             // wave: h-row h0+mhalf, cols rot*64..+64
    int h = h0 + mhalf;
    const char* bb = (const char*)ball;

#pragma unroll 1
    for (int j = 0; j < 9; j++) {
        int dy = ((0x1A901 >> (2 * j)) & 3) - 1;
        int dx = ((0x01A91 >> (2 * j)) & 3) - 1;
        int t = (j == 0) ? 0 : (1 + ((j - 1 - 2 * rot) & 7));
        int r4 = mhalf + dy + 1;
        const char* arow = lds + r4 * 33792;

        short8 Bf[4][8];                               // full K in regs, loaded once per j
#pragma unroll
        for (int ct = 0; ct < 4; ct++) {
            const char* bp = bb + j * 131072 + (rot * 64 + ct * 16 + l15) * 512 + l4 * 16;
#pragma unroll
            for (int ks = 0; ks < 8; ks++) Bf[ct][ks] = *(const short8*)(bp + ks * 64);
        }

        size_t outb = ((size_t)(n * 576 + t * 64) * 4 + rot) * 4096 + (size_t)h * 64;
#pragma unroll
        for (int mt = 0; mt < 4; mt++) {
            int ws = mt * 16 + l15 + dx + 1;           // pixel&63 = mt*16+l15
            const char* ap = arow + ws * 512;
            int key = ws & 7;
            short8 Af[8];
#pragma unroll
            for (int ks = 0; ks < 8; ks++) {
                int s = ks * 4 + l4;
                Af[ks] = *(const short8*)(ap + ((s ^ key) << 4));
            }
            f32x4 a0 = {0.f,0.f,0.f,0.f}, a1 = {0.f,0.f,0.f,0.f};
            f32x4 a2 = {0.f,0.f,0.f,0.f}, a3 = {0.f,0.f,0.f,0.f};
#pragma unroll
            for (int ks = 0; ks < 8; ks++) {
                a0 = __builtin_amdgcn_mfma_f32_16x16x32_bf16(Af[ks], Bf[0][ks], a0, 0, 0, 0);
                a1 = __builtin_amdgcn_mfma_f32_16x16x32_bf16(Af[ks], Bf[1][ks], a1, 0, 0, 0);
                a2 = __builtin_amdgcn_mfma_f32_16x16x32_bf16(Af[ks], Bf[2][ks], a2, 0, 0, 0);
                a3 = __builtin_amdgcn_mfma_f32_16x16x32_bf16(Af[ks], Bf[3][ks], a3, 0, 0, 0);
            }
            int wb = mt * 16 + 4 * l4;                 // D row -> w position
            float* ob = out + outb + wb;
            *(f32x4*)(ob + (size_t)(0 * 16 + l15) * 16384) = a0;
            *(f32x4*)(ob + (size_t)(1 * 16 + l15) * 16384) = a1;
            *(f32x4*)(ob + (size_t)(2 * 16 + l15) * 16384) = a2;
            *(f32x4*)(ob + (size_t)(3 * 16 + l15) * 16384) = a3;
        }
    }
}

// ---------------- fallback (ws too small): direct fp32 ----------------
__global__ __launch_bounds__(256) void k_naive(const float* __restrict__ x,
                                               const float* __restrict__ wgt,
                                               float* __restrict__ out) {
    int idx = blockIdx.x * 256 + threadIdx.x;
    if (idx >= 75497472) return;
    int w = idx & 63, h = (idx >> 6) & 63, rot = (idx >> 12) & 3;
    int chn = idx >> 14; int ch = chn % 576; int n = chn / 576;
    int t = ch >> 6, o = ch & 63;
    int dy = 0, dx = 0;
    if (t > 0) {
        int ri = (t - 1 + 2 * rot) & 7;
        dy = ((27200 >> (2 * ri)) & 3) - 1;
        dx = ((1700 >> (2 * ri)) & 3) - 1;
    }
    int hh = h + dy, ww = w + dx;
    float acc = 0.f;
    if (hh >= 0 && hh < 64 && ww >= 0 && ww < 64) {
        for (int r = 0; r < 4; r++) {
            int rr = (r - rot) & 3;
            for (int c = 0; c < 64; c++)
                acc += x[(((n * 64 + c) * 4 + r) * 64 + hh) * 64 + ww] *
                       wgt[((o * 64 + c) * 4 + rr) * 9 + t];
        }
    }
    out[idx] = acc;
}

extern "C" void kernel_launch(void* const* d_in, const int* in_sizes, int n_in,
                              void* d_out, int out_size, void* d_ws, size_t ws_size,
                              hipStream_t stream) {
    const float* x = (const float*)d_in[0];
    const float* wgt = (const float*)d_in[1];
    float* out = (float*)d_out;
    const size_t XT_BYTES = (size_t)8 * 66 * 64 * 256 * 2;    // 17,301,504
    const size_t NEED = XT_BYTES + (size_t)9 * 256 * 256 * 2; // + 1,179,648
    if (ws_size < NEED) {
        k_naive<<<(75497472 + 255) / 256, 256, 0, stream>>>(x, wgt, out);
        return;
    }
    unsigned short* xt = (unsigned short*)d_ws;
    unsigned short* ball = (unsigned short*)((char*)d_ws + XT_BYTES);
    k_prep<<<2944, 256, 0, stream>>>(x, wgt, xt, ball);
    k_main<<<256, 512, 135168, stream>>>(xt, ball, out);
}

// Round 9
// 94.886 us; speedup vs baseline: 1.3000x; 1.3000x over previous
//
#include <hip/hip_runtime.h>
#include <stdint.h>

using short8 = __attribute__((ext_vector_type(8))) short;
using f32x4  = __attribute__((ext_vector_type(4))) float;

__device__ __forceinline__ unsigned short f2bf(float f) {
    unsigned int u = __float_as_uint(f);
    unsigned int r = (u + 0x7fffu + ((u >> 16) & 1u)) >> 16;
    return (unsigned short)r;
}

// ---------------- prep: [0,512) transpose x -> x_t ; [512,640) zero pad rows ; [640,2944) build B ----------------
__global__ __launch_bounds__(256) void k_prep(const float* __restrict__ x,
                                              const float* __restrict__ wgt,
                                              unsigned short* __restrict__ xt,
                                              unsigned short* __restrict__ ball) {
    __shared__ unsigned short sm[256][72];
    int b = blockIdx.x;
    int tid = threadIdx.x;
    if (b < 512) {
        int n = b >> 6; int h = b & 63;
        int c = tid >> 2, r = tid & 3; int k = r * 64 + c;
        const float* src = x + ((((size_t)n * 64 + c) * 4 + r) * 64 + h) * 64;
#pragma unroll
        for (int i = 0; i < 64; i += 4) {
            float4 v = *(const float4*)(src + i);
            sm[k][i + 0] = f2bf(v.x); sm[k][i + 1] = f2bf(v.y);
            sm[k][i + 2] = f2bf(v.z); sm[k][i + 3] = f2bf(v.w);
        }
        __syncthreads();
        int w = tid & 63, kg = tid >> 6;
        unsigned short* dst = xt + ((size_t)(n * 66 + (h + 1)) * 64 + w) * 256;
        int key = (w + 1) & 7;
#pragma unroll
        for (int cc = 0; cc < 8; cc++) {
            int s = kg * 8 + cc; int sp = s ^ key;
            short8 v;
#pragma unroll
            for (int e = 0; e < 8; e++) v[e] = (short)sm[s * 8 + e][w];
            *(short8*)(dst + sp * 8) = v;
        }
    } else if (b < 640) {
        int idx = (b - 512) * 256 + tid;
        int n = idx >> 12; int rr = (idx >> 11) & 1; int cpos = idx & 2047;
        f32x4 z = {0.f, 0.f, 0.f, 0.f};
        *(f32x4*)((char*)xt + (size_t)(n * 66 + (rr ? 65 : 0)) * 32768 + cpos * 16) = z;
    } else {
        int idx = (b - 640) * 256 + tid;
        int k = idx & 255; int col = (idx >> 8) & 255; int j = idx >> 16;
        int rot = col >> 6, o = col & 63;
        int r = k >> 6, c = k & 63;
        int t = (j == 0) ? 0 : (1 + ((j - 1 - 2 * rot) & 7));
        float v = wgt[((o * 64 + c) * 4 + ((r - rot) & 3)) * 9 + t];
        ball[idx] = f2bf(v);
    }
}

// ---------------- main: R4 structure + double-buffered B prefetch across j ----------------
__global__ __launch_bounds__(512) void k_main(const unsigned short* __restrict__ xt,
                                              const unsigned short* __restrict__ ball,
                                              float* __restrict__ out) {
    extern __shared__ char lds[];                      // 4 rows x 66 slots x 512B = 135168
    int blk = blockIdx.x; int n = blk >> 5; int h0 = (blk & 31) * 2;
    int tid = threadIdx.x;

    // stage 4 x_t rows via async global->LDS (R4-verbatim)
    const char* xbase = (const char*)xt;
#pragma unroll
    for (int i = 0; i < 16; i++) {
        int chunk = tid + i * 512;
        int r4 = chunk >> 11; int cin = chunk & 2047;
        const char* src = xbase + (size_t)(n * 66 + h0 + r4) * 32768 + cin * 16;
        char* dst = lds + r4 * 33792 + 512 + cin * 16;
        __builtin_amdgcn_global_load_lds(
            (const __attribute__((address_space(1))) unsigned int*)src,
            (__attribute__((address_space(3))) unsigned int*)dst, 16, 0, 0);
    }
    if (tid < 256) {                                   // zero the w-halo slots (ws=0, ws=65)
        int r4 = tid >> 6; int sp = (tid >> 5) & 1; int cc = tid & 31;
        f32x4 z = {0.f, 0.f, 0.f, 0.f};
        *(f32x4*)(lds + r4 * 33792 + (sp ? 65 * 512 : 0) + cc * 16) = z;
    }
    __syncthreads();

    int wv = tid >> 6; int l = tid & 63; int l15 = l & 15; int l4 = l >> 4;
    int rot = wv >> 1;                                 // wave owns cols [wv*32, wv*32+32)
    const char* bb = (const char*)ball;

    short8 Bcur[2][8], Bnxt[2][8];
#pragma unroll
    for (int ct = 0; ct < 2; ct++) {
        int col = wv * 32 + ct * 16 + l15;
        const char* bp = bb + col * 512 + l4 * 16;     // j = 0
#pragma unroll
        for (int ks = 0; ks < 8; ks++) Bcur[ct][ks] = *(const short8*)(bp + ks * 64);
    }

#pragma unroll 1
    for (int j = 0; j < 9; j++) {
        int dy = ((0x1A901 >> (2 * j)) & 3) - 1;
        int dx = ((0x01A91 >> (2 * j)) & 3) - 1;
        int t = (j == 0) ? 0 : (1 + ((j - 1 - 2 * rot) & 7));

        if (j < 8) {                                   // prefetch next-j B; consumed only at rotate
#pragma unroll
            for (int ct = 0; ct < 2; ct++) {
                int col = wv * 32 + ct * 16 + l15;
                const char* bp = bb + (j + 1) * 131072 + col * 512 + l4 * 16;
#pragma unroll
                for (int ks = 0; ks < 8; ks++) Bnxt[ct][ks] = *(const short8*)(bp + ks * 64);
            }
        }

#pragma unroll 1
        for (int mtp = 0; mtp < 4; mtp++) {
            short8 Af[2][8];
#pragma unroll
            for (int m2 = 0; m2 < 2; m2++) {
                int mt = mtp * 2 + m2;
                int pixel = mt * 16 + l15;
                int r4 = (pixel >> 6) + dy + 1;
                int ws = (pixel & 63) + dx + 1;
                const char* ap = lds + (r4 * 66 + ws) * 512;
                int key = ws & 7;
#pragma unroll
                for (int ks = 0; ks < 8; ks++) {
                    int s = ks * 4 + l4;
                    Af[m2][ks] = *(const short8*)(ap + ((s ^ key) << 4));
                }
            }
            f32x4 acc[2][2];
#pragma unroll
            for (int a = 0; a < 2; a++)
#pragma unroll
                for (int b2 = 0; b2 < 2; b2++) acc[a][b2] = (f32x4){0.f, 0.f, 0.f, 0.f};
#pragma unroll
            for (int ks = 0; ks < 8; ks++)
#pragma unroll
                for (int ct = 0; ct < 2; ct++)
#pragma unroll
                    for (int m2 = 0; m2 < 2; m2++)
                        acc[ct][m2] = __builtin_amdgcn_mfma_f32_16x16x32_bf16(
                            Af[m2][ks], Bcur[ct][ks], acc[ct][m2], 0, 0, 0);
#pragma unroll
            for (int ct = 0; ct < 2; ct++) {
                int o = (wv & 1) * 32 + ct * 16 + l15;
#pragma unroll
                for (int m2 = 0; m2 < 2; m2++) {
                    int mt = mtp * 2 + m2;
                    int pb = mt * 16 + 4 * l4;
                    int h = h0 + (mt >> 2);
                    int wb = pb & 63;
                    int idx = (((n * 576 + t * 64 + o) * 4 + rot) * 64 + h) * 64 + wb;
                    *(f32x4*)(out + idx) = acc[ct][m2];
                }
            }
        }

        if (j < 8) {                                   // rotate prefetched B into Bcur
#pragma unroll
            for (int ct = 0; ct < 2; ct++)
#pragma unroll
                for (int ks = 0; ks < 8; ks++) Bcur[ct][ks] = Bnxt[ct][ks];
        }
    }
}

// ---------------- fallback (ws too small): direct fp32 ----------------
__global__ __launch_bounds__(256) void k_naive(const float* __restrict__ x,
                                               const float* __restrict__ wgt,
                                               float* __restrict__ out) {
    int idx = blockIdx.x * 256 + threadIdx.x;
    if (idx >= 75497472) return;
    int w = idx & 63, h = (idx >> 6) & 63, rot = (idx >> 12) & 3;
    int chn = idx >> 14; int ch = chn % 576; int n = chn / 576;
    int t = ch >> 6, o = ch & 63;
    int dy = 0, dx = 0;
    if (t > 0) {
        int ri = (t - 1 + 2 * rot) & 7;
        dy = ((27200 >> (2 * ri)) & 3) - 1;
        dx = ((1700 >> (2 * ri)) & 3) - 1;
    }
    int hh = h + dy, ww = w + dx;
    float acc = 0.f;
    if (hh >= 0 && hh < 64 && ww >= 0 && ww < 64) {
        for (int r = 0; r < 4; r++) {
            int rr = (r - rot) & 3;
            for (int c = 0; c < 64; c++)
                acc += x[(((n * 64 + c) * 4 + r) * 64 + hh) * 64 + ww] *
                       wgt[((o * 64 + c) * 4 + rr) * 9 + t];
        }
    }
    out[idx] = acc;
}

extern "C" void kernel_launch(void* const* d_in, const int* in_sizes, int n_in,
                              void* d_out, int out_size, void* d_ws, size_t ws_size,
                              hipStream_t stream) {
    const float* x = (const float*)d_in[0];
    const float* wgt = (const float*)d_in[1];
    float* out = (float*)d_out;
    const size_t XT_BYTES = (size_t)8 * 66 * 64 * 256 * 2;    // 17,301,504
    const size_t NEED = XT_BYTES + (size_t)9 * 256 * 256 * 2; // + 1,179,648
    if (ws_size < NEED) {
        k_naive<<<(75497472 + 255) / 256, 256, 0, stream>>>(x, wgt, out);
        return;
    }
    unsigned short* xt = (unsigned short*)d_ws;
    unsigned short* ball = (unsigned short*)((char*)d_ws + XT_BYTES);
    k_prep<<<2944, 256, 0, stream>>>(x, wgt, xt, ball);
    k_main<<<256, 512, 135168, stream>>>(xt, ball, out);
}

// Round 10
// 83.838 us; speedup vs baseline: 1.4714x; 1.1318x over previous
//
#include <hip/hip_runtime.h>
#include <stdint.h>

using short8 = __attribute__((ext_vector_type(8))) short;
using f32x4  = __attribute__((ext_vector_type(4))) float;

__device__ __forceinline__ unsigned short f2bf(float f) {
    unsigned int u = __float_as_uint(f);
    unsigned int r = (u + 0x7fffu + ((u >> 16) & 1u)) >> 16;
    return (unsigned short)r;
}

// ---------------- wprep: B_all[off][col=rot*64+o][k=r*64+c] = wgt[o][c][(r-rot)&3][t(off,rot)] ----------------
__global__ __launch_bounds__(256) void k_wprep(const float* __restrict__ wgt,
                                               unsigned short* __restrict__ ball) {
    int idx = blockIdx.x * 256 + threadIdx.x;          // 589824 elems
    int k = idx & 255; int col = (idx >> 8) & 255; int j = idx >> 16;
    int rot = col >> 6, o = col & 63;
    int r = k >> 6, c = k & 63;
    int t = (j == 0) ? 0 : (1 + ((j - 1 - 2 * rot) & 7));
    float v = wgt[((o * 64 + c) * 4 + ((r - rot) & 3)) * 9 + t];
    ball[idx] = f2bf(v);
}

// ---------------- fused main: per-block transpose-stage from x, then R4 main loop ----------------
// A-panel LDS layout (R4-identical): (r4*66 + ws)*512 + chunk_swizzled; rows h0-1..h0+2, w-halo zeroed.
__global__ __launch_bounds__(512) void k_main(const float* __restrict__ x,
                                              const unsigned short* __restrict__ ball,
                                              float* __restrict__ out) {
    extern __shared__ char lds[];                      // 135168 A-panel + 16896 bounce = 152064
    int d = blockIdx.x;
    int orig = (d & 7) * 32 + (d >> 3);                // XCD-chunked: XCD x owns all h-blocks of n=x
    int n = orig >> 5; int h0 = (orig & 31) * 2;
    int tid = threadIdx.x;
    unsigned short* smu = (unsigned short*)(lds + 135168);   // bounce [128][66] u16

    // zero the w-halo slots (ws=0, ws=65) of the A-panel
    if (tid < 256) {
        int r4 = tid >> 6; int sp = (tid >> 5) & 1; int cc = tid & 31;
        f32x4 z = {0.f, 0.f, 0.f, 0.f};
        *(f32x4*)(lds + r4 * 33792 + (sp ? 65 * 512 : 0) + cc * 16) = z;
    }

    // stage: transpose x[n][c][r][hh][w] -> A-panel, 4 rows x 2 k-halves
    int wA = tid & 63; int kq = tid >> 6;              // phase A: thread = (kq, w)
#pragma unroll 1
    for (int r4 = 0; r4 < 4; r4++) {
        int hh = h0 - 1 + r4;
        bool ok = ((unsigned)hh < 64u);
#pragma unroll 1
        for (int half = 0; half < 2; half++) {
            // phase A: 128 k x 64 w -> bounce (w-contiguous writes, conflict-free)
            if (ok) {
#pragma unroll
                for (int e = 0; e < 16; e++) {
                    int kl = kq * 16 + e;
                    int k = half * 128 + kl;
                    int r = k >> 6, c = k & 63;
                    float v = x[(((n * 64 + c) * 4 + r) * 64 + hh) * 64 + wA];
                    smu[kl * 66 + wA] = f2bf(v);
                }
            } else {
#pragma unroll
                for (int e = 0; e < 16; e++) smu[(kq * 16 + e) * 66 + wA] = 0;
            }
            __syncthreads();
            // phase B: repack k-major short8 chunks into swizzled A-panel
            {
                int w = tid & 63; int q = tid >> 6;
                int key = (w + 1) & 7;
                char* prow = lds + (r4 * 66 + (w + 1)) * 512;
#pragma unroll
                for (int ss = 0; ss < 2; ss++) {
                    int sl = q + ss * 8;               // 0..15
                    int sg = half * 16 + sl;           // global chunk: k = sg*8+e
                    short8 vv;
#pragma unroll
                    for (int e = 0; e < 8; e++) vv[e] = (short)smu[(sl * 8 + e) * 66 + w];
                    *(short8*)(prow + ((sg ^ key) << 4)) = vv;
                }
            }
            __syncthreads();
        }
    }

    // ---------------- main loop: R4-verbatim ----------------
    int wv = tid >> 6; int l = tid & 63; int l15 = l & 15; int l4 = l >> 4;
    int rot = wv >> 1;                                 // wave owns cols [wv*32, wv*32+32)
    const char* bb = (const char*)ball;

    for (int j = 0; j < 9; j++) {
        int dy = ((0x1A901 >> (2 * j)) & 3) - 1;
        int dx = ((0x01A91 >> (2 * j)) & 3) - 1;
        int t = (j == 0) ? 0 : (1 + ((j - 1 - 2 * rot) & 7));

        short8 Bf[2][8];
#pragma unroll
        for (int ct = 0; ct < 2; ct++) {
            int col = wv * 32 + ct * 16 + l15;
            const char* bp = bb + j * 131072 + col * 512 + l4 * 16;
#pragma unroll
            for (int ks = 0; ks < 8; ks++) Bf[ct][ks] = *(const short8*)(bp + ks * 64);
        }

#pragma unroll 1
        for (int mtp = 0; mtp < 4; mtp++) {
            short8 Af[2][8];
#pragma unroll
            for (int m2 = 0; m2 < 2; m2++) {
                int mt = mtp * 2 + m2;
                int pixel = mt * 16 + l15;
                int r4 = (pixel >> 6) + dy + 1;
                int ws = (pixel & 63) + dx + 1;
                const char* ap = lds + (r4 * 66 + ws) * 512;
                int key = ws & 7;
#pragma unroll
                for (int ks = 0; ks < 8; ks++) {
                    int s = ks * 4 + l4;
                    Af[m2][ks] = *(const short8*)(ap + ((s ^ key) << 4));
                }
            }
            f32x4 acc[2][2];
#pragma unroll
            for (int a = 0; a < 2; a++)
#pragma unroll
                for (int b2 = 0; b2 < 2; b2++) acc[a][b2] = (f32x4){0.f, 0.f, 0.f, 0.f};
#pragma unroll
            for (int ks = 0; ks < 8; ks++)
#pragma unroll
                for (int ct = 0; ct < 2; ct++)
#pragma unroll
                    for (int m2 = 0; m2 < 2; m2++)
                        acc[ct][m2] = __builtin_amdgcn_mfma_f32_16x16x32_bf16(
                            Af[m2][ks], Bf[ct][ks], acc[ct][m2], 0, 0, 0);
#pragma unroll
            for (int ct = 0; ct < 2; ct++) {
                int o = (wv & 1) * 32 + ct * 16 + l15;
#pragma unroll
                for (int m2 = 0; m2 < 2; m2++) {
                    int mt = mtp * 2 + m2;
                    int pb = mt * 16 + 4 * l4;
                    int h = h0 + (mt >> 2);
                    int wb = pb & 63;
                    int idx = (((n * 576 + t * 64 + o) * 4 + rot) * 64 + h) * 64 + wb;
                    *(f32x4*)(out + idx) = acc[ct][m2];
                }
            }
        }
    }
}

// ---------------- fallback (ws too small): direct fp32 ----------------
__global__ __launch_bounds__(256) void k_naive(const float* __restrict__ x,
                                               const float* __restrict__ wgt,
                                               float* __restrict__ out) {
    int idx = blockIdx.x * 256 + threadIdx.x;
    if (idx >= 75497472) return;
    int w = idx & 63, h = (idx >> 6) & 63, rot = (idx >> 12) & 3;
    int chn = idx >> 14; int ch = chn % 576; int n = chn / 576;
    int t = ch >> 6, o = ch & 63;
    int dy = 0, dx = 0;
    if (t > 0) {
        int ri = (t - 1 + 2 * rot) & 7;
        dy = ((27200 >> (2 * ri)) & 3) - 1;
        dx = ((1700 >> (2 * ri)) & 3) - 1;
    }
    int hh = h + dy, ww = w + dx;
    float acc = 0.f;
    if (hh >= 0 && hh < 64 && ww >= 0 && ww < 64) {
        for (int r = 0; r < 4; r++) {
            int rr = (r - rot) & 3;
            for (int c = 0; c < 64; c++)
                acc += x[(((n * 64 + c) * 4 + r) * 64 + hh) * 64 + ww] *
                       wgt[((o * 64 + c) * 4 + rr) * 9 + t];
        }
    }
    out[idx] = acc;
}

extern "C" void kernel_launch(void* const* d_in, const int* in_sizes, int n_in,
                              void* d_out, int out_size, void* d_ws, size_t ws_size,
                              hipStream_t stream) {
    const float* x = (const float*)d_in[0];
    const float* wgt = (const float*)d_in[1];
    float* out = (float*)d_out;
    const size_t NEED = (size_t)9 * 256 * 256 * 2;     // 1,179,648 (ball only; x_t eliminated)
    if (ws_size < NEED) {
        k_naive<<<(75497472 + 255) / 256, 256, 0, stream>>>(x, wgt, out);
        return;
    }
    unsigned short* ball = (unsigned short*)d_ws;
    k_wprep<<<2304, 256, 0, stream>>>(wgt, ball);
    k_main<<<256, 512, 152064, stream>>>(x, ball, out);
}